// Round 13
// baseline (1165.248 us; speedup 1.0000x reference)
//
#include <hip/hip_runtime.h>
#include <hip/hip_bf16.h>

// Problem constants
#define NN 50000
#define EE 800000
#define GG 1024
#define DD 300
#define DP 320        // padded feature dim for GEMM-A (multiple of 32 for MFMA K)
#define HS 304        // HW (gemm-out) row stride: 304 dims = 608 B, 16B-aligned
#define LL 5
#define FEAT 256

#define AGGB 3136     // agg blocks: 16 nodes/block (4/wave); 3136 = 64*49

typedef __bf16 bf16x8 __attribute__((ext_vector_type(8)));
typedef float  f32x4  __attribute__((ext_vector_type(4)));

#define AS1 __attribute__((address_space(1)))
#define AS3 __attribute__((address_space(3)))

// async global->LDS, 16B per lane; LDS dst must be wave-uniform base + lane*16
__device__ __forceinline__ void dma16(const __hip_bfloat16* g, __hip_bfloat16* l) {
    auto gp = reinterpret_cast<const AS1 char*>(reinterpret_cast<uintptr_t>(g));
    auto lp = reinterpret_cast<AS3 char*>((unsigned int)(uintptr_t)l);
    __builtin_amdgcn_global_load_lds(gp, lp, 16, 0, 0);
}

// unpack 8 bf16 (int4) and add into 8 f32 accumulators
__device__ __forceinline__ void addbf8(float* a, int4 q) {
    unsigned int u;
    u = (unsigned int)q.x;
    a[0] += __uint_as_float(u << 16); a[1] += __uint_as_float(u & 0xFFFF0000u);
    u = (unsigned int)q.y;
    a[2] += __uint_as_float(u << 16); a[3] += __uint_as_float(u & 0xFFFF0000u);
    u = (unsigned int)q.z;
    a[4] += __uint_as_float(u << 16); a[5] += __uint_as_float(u & 0xFFFF0000u);
    u = (unsigned int)q.w;
    a[6] += __uint_as_float(u << 16); a[7] += __uint_as_float(u & 0xFFFF0000u);
}

// ---------------------------------------------------------------------------
__global__ void hist_kernel(const int* __restrict__ ei, int* __restrict__ deg) {
    int e = blockIdx.x * 256 + threadIdx.x;
    atomicAdd(&deg[ei[EE + e]], 1);
}

__global__ void scan1_kernel(const int* __restrict__ deg, int* __restrict__ ptr,
                             int* __restrict__ bsum) {
    __shared__ int buf[256];
    int tid = threadIdx.x;
    int i = blockIdx.x * 256 + tid;
    int v = (i < NN) ? deg[i] : 0;
    buf[tid] = v; __syncthreads();
    for (int off = 1; off < 256; off <<= 1) {
        int t = (tid >= off) ? buf[tid - off] : 0;
        __syncthreads();
        buf[tid] += t;
        __syncthreads();
    }
    if (i < NN) ptr[i + 1] = buf[tid];     // inclusive within block
    if (tid == 255) bsum[blockIdx.x] = buf[255];
}

__global__ void scan2_kernel(int* __restrict__ bsum) {   // 196 block sums -> exclusive
    __shared__ int buf[256];
    int tid = threadIdx.x;
    int v = (tid < 196) ? bsum[tid] : 0;
    buf[tid] = v; __syncthreads();
    for (int off = 1; off < 256; off <<= 1) {
        int t = (tid >= off) ? buf[tid - off] : 0;
        __syncthreads();
        buf[tid] += t;
        __syncthreads();
    }
    if (tid < 196) bsum[tid] = buf[tid] - v;  // exclusive
}

__global__ void scan3_kernel(int* __restrict__ ptr, const int* __restrict__ bsum) {
    int i = blockIdx.x * 256 + threadIdx.x;
    if (i < NN) ptr[i + 1] += bsum[blockIdx.x];
    if (i == 0) ptr[0] = 0;
}

// ---------------------------------------------------------------------------
// scatter edges into CSC src list; attrs packed into spare bits (r<65536).
__global__ void scatter_kernel(const int* __restrict__ ei, const int* __restrict__ ea,
                               const int* __restrict__ ptr, int* __restrict__ cur,
                               int* __restrict__ srcout) {
    int e = blockIdx.x * 256 + threadIdx.x;
    int r = ei[e], c = ei[EE + e];
    int a0 = ea[e * 2 + 0], a1 = ea[e * 2 + 1];
    int pos = ptr[c] + atomicAdd(&cur[c], 1);
    srcout[pos] = r | (a0 << 16) | (a1 << 18);
}

// ---------------------------------------------------------------------------
// per-node per-layer edge-scalar sums, no atomics
__global__ void sv_kernel(const int* __restrict__ ptr, const int* __restrict__ src,
                          const float* __restrict__ e1, const float* __restrict__ e2,
                          float* __restrict__ SV) {
    int v = blockIdx.x * 256 + threadIdx.x;
    if (v >= NN) return;
    float c00 = 0.f, c01 = 0.f, c02 = 0.f, c10 = 0.f, c11 = 0.f, c12 = 0.f;
    int beg = ptr[v], end = ptr[v + 1];
    for (int i = beg; i < end; ++i) {
        int p = src[i];
        int e0 = (p >> 16) & 3, ev = (p >> 18) & 3;
        c00 += (e0 == 0); c01 += (e0 == 1); c02 += (e0 == 2);
        c10 += (ev == 0); c11 += (ev == 1); c12 += (ev == 2);
    }
#pragma unroll
    for (int l = 0; l < LL; ++l) {
        float s = c00 * e1[l * 5 + 0] + c01 * e1[l * 5 + 1] + c02 * e1[l * 5 + 2]
                + c10 * e2[l * 3 + 0] + c11 * e2[l * 3 + 1] + c12 * e2[l * 3 + 2];
        SV[l * NN + v] = s;
    }
}

// ---------------------------------------------------------------------------
// repack W[l] (k,n row-major, 300x300 f32) into TILED+SWIZZLED bf16 WT for BK=64
// (r10-proven layout): [l][ntile(2)][ktile(5)][nn(160) x 8 pu x 8 el]; the 16B
// unit at (nn,pu) holds logical k-unit u = pu ^ (nn&7), k = ktile*64 + u*8..+7.
__global__ void repack_kernel(const float* __restrict__ W,
                              __hip_bfloat16* __restrict__ WT) {
    int idx = blockIdx.x * 256 + threadIdx.x;       // < LL*DP*DP
    int l = idx / (DP * DP);
    int r = idx - l * DP * DP;
    int ntile = r / 51200; r -= ntile * 51200;
    int ktile = r / 10240; r -= ktile * 10240;
    int nn = r >> 6; r &= 63;
    int pu = r >> 3; int e = r & 7;
    int u = pu ^ (nn & 7);                 // logical k-unit stored at this slot
    int n = ntile * 160 + nn;
    int k = ktile * 64 + u * 8 + e;
    float v = 0.f;
    if (n < DD && k < DD) v = W[l * DD * DD + k * DD + n];
    WT[idx] = __float2bfloat16(v);
}

// ---------------------------------------------------------------------------
// GEMM (r10-proven structure): C[M x HS(304)] = act(A[M x 320]) @ B. BK=64,
// grid (391,2). B pre-tiled/swizzled, staged via global_load_lds (16B DMA).
// mode==1: act(x) = relu(x*scale[k]+shift[k]) folded into A-staging.
// mode==2: A is the node EMBEDDING computed on the fly from x/emb1/emb2.
// Output written in the 608-byte agg-friendly row format (dims 0..303; B-pad
// cols are exact zeros). Epilogue: LDS-staged coalesced 16B stores.
__global__ __launch_bounds__(256) void gemm_kernel(
        const __hip_bfloat16* __restrict__ A, const __hip_bfloat16* __restrict__ BT,
        __hip_bfloat16* __restrict__ C, int M,
        const float* __restrict__ scale, const float* __restrict__ shift,
        const int* __restrict__ x, const float* __restrict__ emb1,
        const float* __restrict__ emb2, int mode) {
    // shared pool: As (128*72*2=18432) + Bs (160*64*2=20480) = 38912 B;
    // epilogue reuses it as 64 rows x stride 168 bf16 (= 21504 B).
    __shared__ __align__(16) char smem[38912];
    __hip_bfloat16* As = reinterpret_cast<__hip_bfloat16*>(smem);            // [128*72]
    __hip_bfloat16* Bs = reinterpret_cast<__hip_bfloat16*>(smem + 18432);    // [160*64]
    __hip_bfloat16* Cs = reinterpret_cast<__hip_bfloat16*>(smem);            // [64*168]
    int tid = threadIdx.x;
    int m0 = blockIdx.x * 128;
    int wave = tid >> 6, lane = tid & 63;
    int wm = (wave >> 1) * 64, wn = (wave & 1) * 80;
    int fm = lane & 15, fu = lane >> 4;     // k-unit 0..3 within a 32-k half

    f32x4 acc[4][5];
#pragma unroll
    for (int i = 0; i < 4; ++i)
#pragma unroll
        for (int j = 0; j < 5; ++j) acc[i][j] = (f32x4){0.f, 0.f, 0.f, 0.f};

    const __hip_bfloat16* btile0 = BT + (size_t)blockIdx.y * 51200;

    for (int k0 = 0; k0 < DP; k0 += 64) {
        __syncthreads();
        // B tile: 1280 x 16B units, async DMA straight to LDS
        const __hip_bfloat16* bt = btile0 + (k0 >> 6) * 10240;
#pragma unroll
        for (int i = 0; i < 5; ++i)
            dma16(bt + (size_t)(tid + i * 256) * 8, Bs + (tid + i * 256) * 8);
        // A tile: VGPR path (BN+relu fold or on-the-fly embedding), 1024 units
#pragma unroll
        for (int u = tid; u < 1024; u += 256) {
            int r = u >> 3, p = u & 7;
            int gr = m0 + r;
            int4 val = make_int4(0, 0, 0, 0);
            if (gr < M) {
                if (mode == 2) {
                    int i0 = x[gr * 2 + 0], i1 = x[gr * 2 + 1];
                    int kb = k0 + p * 8;
                    union { int4 i4; __hip_bfloat16 h[8]; } o;
#pragma unroll
                    for (int j4 = 0; j4 < 2; ++j4) {
                        int kk = kb + j4 * 4;
                        if (kk + 3 < DD) {   // i0*300*4 and kk*4 are 16B-aligned
                            float4 ea = *reinterpret_cast<const float4*>(emb1 + i0 * DD + kk);
                            float4 eb = *reinterpret_cast<const float4*>(emb2 + i1 * DD + kk);
                            o.h[j4 * 4 + 0] = __float2bfloat16(ea.x + eb.x);
                            o.h[j4 * 4 + 1] = __float2bfloat16(ea.y + eb.y);
                            o.h[j4 * 4 + 2] = __float2bfloat16(ea.z + eb.z);
                            o.h[j4 * 4 + 3] = __float2bfloat16(ea.w + eb.w);
                        } else {
#pragma unroll
                            for (int j = 0; j < 4; ++j) {
                                int k = kk + j;
                                float v = (k < DD) ? emb1[i0 * DD + k] + emb2[i1 * DD + k]
                                                   : 0.f;
                                o.h[j4 * 4 + j] = __float2bfloat16(v);
                            }
                        }
                    }
                    val = o.i4;
                } else {
                    val = *reinterpret_cast<const int4*>(A + (size_t)gr * DP + k0 + p * 8);
                    if (mode == 1) {
                        __hip_bfloat16* hh = reinterpret_cast<__hip_bfloat16*>(&val);
                        int kb = k0 + p * 8;
#pragma unroll
                        for (int j = 0; j < 8; ++j) {
                            float f = fmaf(__bfloat162float(hh[j]), scale[kb + j], shift[kb + j]);
                            hh[j] = __float2bfloat16(fmaxf(f, 0.f));
                        }
                    }
                }
            }
            *reinterpret_cast<int4*>(As + r * 72 + p * 8) = val;
        }
        __syncthreads();
#pragma unroll
        for (int h = 0; h < 2; ++h) {
            bf16x8 af[4], bfr[5];
#pragma unroll
            for (int mt = 0; mt < 4; ++mt)
                af[mt] = *reinterpret_cast<const bf16x8*>(
                    As + (wm + mt * 16 + fm) * 72 + h * 32 + fu * 8);
#pragma unroll
            for (int nt = 0; nt < 5; ++nt) {
                int n = wn + nt * 16 + fm;
                int pu = (h * 4 + fu) ^ (n & 7);
                bfr[nt] = *reinterpret_cast<const bf16x8*>(Bs + n * 64 + pu * 8);
            }
#pragma unroll
            for (int mt = 0; mt < 4; ++mt)
#pragma unroll
                for (int nt = 0; nt < 5; ++nt)
                    acc[mt][nt] = __builtin_amdgcn_mfma_f32_16x16x32_bf16(
                        af[mt], bfr[nt], acc[mt][nt], 0, 0, 0);
        }
    }
    // epilogue via LDS: C/D layout col=lane&15, row=(lane>>4)*4+reg [m89-verified].
    // y-block 0 -> row units 0..19 (cols 0..159); y-block 1 -> units 20..37
    // (cols 160..303; cols 304..319 are pad, dropped).
    int base_u = blockIdx.y * 20;
    int cc = lane & 15, cr = (lane >> 4) * 4;
#pragma unroll
    for (int h = 0; h < 2; ++h) {
        __syncthreads();
        if ((wave >> 1) == h) {
#pragma unroll
            for (int mt = 0; mt < 4; ++mt)
#pragma unroll
                for (int nt = 0; nt < 5; ++nt)
#pragma unroll
                    for (int r = 0; r < 4; ++r)
                        Cs[(mt * 16 + cr + r) * 168 + wn + nt * 16 + cc] =
                            __float2bfloat16(acc[mt][nt][r]);
        }
        __syncthreads();
#pragma unroll
        for (int u = tid; u < 1280; u += 256) {
            int r = u / 20, c16 = u % 20;
            int gu = base_u + c16;
            int row = m0 + h * 64 + r;
            if (row < M && gu < 38)
                *reinterpret_cast<int4*>(C + (size_t)row * HS + gu * 8) =
                    *reinterpret_cast<const int4*>(Cs + r * 168 + c16 * 8);
        }
    }
}

// ---------------------------------------------------------------------------
// aggregation + fused BN stats, ONE 16B load per edge-row:
// HW rows are 608 B (304 dims); lane L (L<38) owns dims 8L..8L+7 via a single
// dwordx4. AGGB blocks x 4 waves x 4 nodes; 4-wide unroll, 4 accumulator sets.
// Writes bf16 h_pre into AH (640-stride GEMM-A layout, pads 0, lanes 0..39).
// Lane BN partials (sum/sumsq of its 8 dims) LDS-reduced to part[block][640].
__global__ __launch_bounds__(256) void agg_kernel(
        const __hip_bfloat16* __restrict__ HW,
        const int* __restrict__ ptr, const int* __restrict__ src,
        const float* __restrict__ SVl, __hip_bfloat16* __restrict__ AH,
        float* __restrict__ part) {
    int w = threadIdx.x >> 6;
    int lane = threadIdx.x & 63;
    bool act = lane < 38;
    const int4 z4 = make_int4(0, 0, 0, 0);
    float bs[8], bq[8];
#pragma unroll
    for (int j = 0; j < 8; ++j) { bs[j] = 0.f; bq[j] = 0.f; }

#pragma unroll
    for (int k = 0; k < 4; ++k) {
        int v = blockIdx.x * 16 + w * 4 + k;
        if (v >= NN) break;
        int beg = ptr[v], end = ptr[v + 1];
        float a0[8], a1[8], a2[8], a3[8];
#pragma unroll
        for (int j = 0; j < 8; ++j) { a0[j] = 0.f; a1[j] = 0.f; a2[j] = 0.f; a3[j] = 0.f; }
        // self term
        {
            int4 q = act ? *reinterpret_cast<const int4*>(HW + (size_t)v * HS + 8 * lane) : z4;
            addbf8(a0, q);
        }
        int i = beg;
        for (; i < end && (i & 3); ++i) {
            int s0 = src[i] & 0xFFFF;
            int4 q = act ? *reinterpret_cast<const int4*>(HW + (size_t)s0 * HS + 8 * lane) : z4;
            addbf8(a0, q);
        }
        for (; i + 4 <= end; i += 4) {
            int4 s4 = *reinterpret_cast<const int4*>(src + i);   // 4 indices, one load
            int s0 = s4.x & 0xFFFF, s1 = s4.y & 0xFFFF;
            int s2 = s4.z & 0xFFFF, s3 = s4.w & 0xFFFF;
            int4 q0 = act ? *reinterpret_cast<const int4*>(HW + (size_t)s0 * HS + 8 * lane) : z4;
            int4 q1 = act ? *reinterpret_cast<const int4*>(HW + (size_t)s1 * HS + 8 * lane) : z4;
            int4 q2 = act ? *reinterpret_cast<const int4*>(HW + (size_t)s2 * HS + 8 * lane) : z4;
            int4 q3 = act ? *reinterpret_cast<const int4*>(HW + (size_t)s3 * HS + 8 * lane) : z4;
            addbf8(a0, q0); addbf8(a1, q1); addbf8(a2, q2); addbf8(a3, q3);
        }
        for (; i < end; ++i) {
            int s0 = src[i] & 0xFFFF;
            int4 q = act ? *reinterpret_cast<const int4*>(HW + (size_t)s0 * HS + 8 * lane) : z4;
            addbf8(a0, q);
        }
        float sv = SVl[v];
        union { int4 i4; __hip_bfloat16 h[8]; } o;
#pragma unroll
        for (int j = 0; j < 8; ++j) {
            int d = 8 * lane + j;
            float r = (d < DD) ? (a0[j] + a1[j] + a2[j] + a3[j] + sv) : 0.f;
            bs[j] += r; bq[j] = fmaf(r, r, bq[j]);
            o.h[j] = __float2bfloat16(r);
        }
        if (lane < 40)        // lanes 0..39 cover AH dims 0..319 (pads get 0)
            *reinterpret_cast<int4*>(AH + (size_t)v * DP + 8 * lane) = o.i4;
    }
    // reduce 4 waves -> per-block partials ([0..319]=sum, [320..639]=sumsq)
    __shared__ float red[4 * 640];    // 10.24 KB
    float* rw_ = red + w * 640;
#pragma unroll
    for (int j = 0; j < 8; ++j) {
        int d = 8 * lane + j;
        if (d < 320) { rw_[d] = bs[j]; rw_[320 + d] = bq[j]; }
    }
    __syncthreads();
    for (int i = threadIdx.x; i < 640; i += 256)
        part[(size_t)blockIdx.x * 640 + i] =
            red[i] + red[640 + i] + red[1280 + i] + red[1920 + i];
}

// reduce AGGB partials -> 64 partials  (AGGB = 64*49)
__global__ void finalize1_kernel(const float* __restrict__ part, float* __restrict__ part2) {
    int b = blockIdx.x;                 // 0..63
    const int K = AGGB / 64;            // 49
    for (int i = threadIdx.x; i < 640; i += 256) {
        float acc = 0.f;
        for (int k = 0; k < K; ++k)
            acc += part[(size_t)(b * K + k) * 640 + i];
        part2[b * 640 + i] = acc;
    }
}

// reduce 64 partials; writes scale/shift for ALL 320 dims (pad dims 0/0)
__global__ void finalize_kernel(const float* __restrict__ part2,
                                const float* __restrict__ gamma_l,
                                const float* __restrict__ beta_l,
                                float* __restrict__ scale, float* __restrict__ shift) {
    int d = threadIdx.x;                 // block of 320
    float sc = 0.f, sh = 0.f;
    if (d < DD) {
        float s = 0.f, q = 0.f;
        for (int b = 0; b < 64; ++b) {
            s += part2[b * 640 + d];
            q += part2[b * 640 + 320 + d];
        }
        const float invN = 1.0f / (float)NN;
        float mean = s * invN;
        float var = q * invN - mean * mean;
        var = fmaxf(var, 0.f);                      // guard fp32 cancellation
        float rs = rsqrtf(var + 1e-5f);
        sc = rs * gamma_l[d];
        sh = beta_l[d] - mean * sc;
    }
    scale[d] = sc;
    shift[d] = sh;
}

// ---------------------------------------------------------------------------
__device__ __forceinline__ int lower_bound_dev(const int* b, int n, int key) {
    int lo = 0, hi = n;
    while (lo < hi) { int mid = (lo + hi) >> 1; if (b[mid] < key) lo = mid + 1; else hi = mid; }
    return lo;
}

// mean pool per graph over raw h_pre (AH, 640-stride), then the last layer's
// BN affine applied after pooling (linear). One wave per graph.
__global__ void pool_kernel(const __hip_bfloat16* __restrict__ A, const int* __restrict__ batch,
                            const float* __restrict__ scale, const float* __restrict__ shift,
                            float* __restrict__ HG) {
    int g = blockIdx.x * 4 + (threadIdx.x >> 6);
    int lane = threadIdx.x & 63;
    bool act = lane < 40;
    int lo = lower_bound_dev(batch, NN, g);
    int hi = lower_bound_dev(batch, NN, g + 1);
    const int4 z4 = make_int4(0, 0, 0, 0);
    float a[8];
#pragma unroll
    for (int j = 0; j < 8; ++j) a[j] = 0.f;
    for (int v = lo; v < hi; ++v) {
        int4 q = act ? *reinterpret_cast<const int4*>(A + (size_t)v * DP + 8 * lane) : z4;
        addbf8(a, q);
    }
    if (act) {
        int cnt = hi - lo;
        float inv = 1.0f / (float)(cnt > 0 ? cnt : 1);
        float* out = HG + (size_t)g * DP;
#pragma unroll
        for (int j = 0; j < 8; ++j) {
            int d = 8 * lane + j;
            out[d] = fmaf(a[j] * inv, scale[d], shift[d]);  // pad dims: 0/0 -> 0
        }
    }
}

// h_feat = hg @ feat_w + feat_b   (one block per graph), f32 out
__global__ void feat_kernel(const float* __restrict__ HG,
                            const float* __restrict__ fw,
                            const float* __restrict__ fb,
                            float* __restrict__ HFEAT, float* __restrict__ out0) {
    __shared__ float hgs[DD];
    int g = blockIdx.x, tid = threadIdx.x;
    for (int i = tid; i < DD; i += 256) hgs[i] = HG[(size_t)g * DP + i];
    __syncthreads();
    float acc = fb[tid];
#pragma unroll 4
    for (int k = 0; k < DD; ++k)
        acc = fmaf(hgs[k], fw[k * FEAT + tid], acc);
    HFEAT[g * FEAT + tid] = acc;
    out0[g * FEAT + tid] = acc;
}

// out = relu(h_feat @ w1 + b1) @ w2 + b2   (one block per graph), f32 out
__global__ void mlp_kernel(const float* __restrict__ HFEAT,
                           const float* __restrict__ w1, const float* __restrict__ b1,
                           const float* __restrict__ w2, const float* __restrict__ b2,
                           float* __restrict__ out1) {
    __shared__ float hf[FEAT], t[FEAT];
    int g = blockIdx.x, tid = threadIdx.x;
    hf[tid] = HFEAT[g * FEAT + tid];
    __syncthreads();
    float acc = b1[tid];
#pragma unroll 4
    for (int k = 0; k < FEAT; ++k)
        acc = fmaf(hf[k], w1[k * FEAT + tid], acc);
    t[tid] = fmaxf(acc, 0.f);
    __syncthreads();
    if (tid < FEAT / 2) {
        float acc2 = b2[tid];
#pragma unroll 4
        for (int k = 0; k < FEAT; ++k)
            acc2 = fmaf(t[k], w2[k * (FEAT / 2) + tid], acc2);
        out1[g * (FEAT / 2) + tid] = acc2;
    }
}

// ---------------------------------------------------------------------------
extern "C" void kernel_launch(void* const* d_in, const int* in_sizes, int n_in,
                              void* d_out, int out_size, void* d_ws, size_t ws_size,
                              hipStream_t stream) {
    const int* x     = (const int*)d_in[0];
    const int* ei    = (const int*)d_in[1];
    const int* ea    = (const int*)d_in[2];
    const int* batch = (const int*)d_in[3];
    const float* emb1  = (const float*)d_in[4];
    const float* emb2  = (const float*)d_in[5];
    const float* W     = (const float*)d_in[6];
    // d_in[7] = b[l]: per-dim constant, cancelled by BatchNorm -> unused
    const float* e1    = (const float*)d_in[8];
    const float* e2    = (const float*)d_in[9];
    const float* gamma = (const float*)d_in[10];
    const float* beta  = (const float*)d_in[11];
    const float* fw    = (const float*)d_in[12];
    const float* fb    = (const float*)d_in[13];
    const float* w1    = (const float*)d_in[14];
    const float* b1    = (const float*)d_in[15];
    const float* w2    = (const float*)d_in[16];
    const float* b2    = (const float*)d_in[17];

    // workspace carve (~78 MB total; small control buffers FIRST)
    char* base = (char*)d_ws;
    size_t off = 0;
    auto carve = [&](size_t bytes) -> void* {
        void* p = base + off;
        off = (off + bytes + 255) & ~(size_t)255;
        return p;
    };
    int*            PTR   = (int*)carve((size_t)(NN + 1) * 4);
    int*            CUR   = (int*)carve((size_t)NN * 4);
    int*            SRC   = (int*)carve((size_t)EE * 4);
    float*          SV    = (float*)carve((size_t)LL * NN * 4);
    int*            BSUM  = (int*)carve(256 * 4);
    float*          PART  = (float*)carve((size_t)AGGB * 640 * 4);
    float*          PART2 = (float*)carve((size_t)64 * 640 * 4);
    float*          SCALE = (float*)carve(DP * 4);
    float*          SHIFT = (float*)carve(DP * 4);
    float*          HG    = (float*)carve((size_t)GG * DP * 4);
    float*          HFEAT = (float*)carve((size_t)GG * FEAT * 4);
    __hip_bfloat16* WT    = (__hip_bfloat16*)carve((size_t)LL * DP * DP * 2);
    __hip_bfloat16* AH    = (__hip_bfloat16*)carve((size_t)NN * DP * 2);  // h_pre (640-stride)
    __hip_bfloat16* HWb   = (__hip_bfloat16*)carve((size_t)NN * HS * 2);  // gemm out (608-stride)

    float* out0 = (float*)d_out;                 // h_feat [G,256] f32
    float* out1 = (float*)d_out + GG * FEAT;     // out    [G,128] f32

    // ---- preprocess (ws is re-poisoned before every call) ----
    hipMemsetAsync(CUR, 0, (size_t)NN * 4, stream);
    hist_kernel<<<EE / 256, 256, 0, stream>>>(ei, CUR);
    scan1_kernel<<<196, 256, 0, stream>>>(CUR, PTR, BSUM);
    scan2_kernel<<<1, 256, 0, stream>>>(BSUM);
    scan3_kernel<<<196, 256, 0, stream>>>(PTR, BSUM);
    hipMemsetAsync(CUR, 0, (size_t)NN * 4, stream);
    scatter_kernel<<<EE / 256, 256, 0, stream>>>(ei, ea, PTR, CUR, SRC);
    sv_kernel<<<196, 256, 0, stream>>>(PTR, SRC, e1, e2, SV);
    repack_kernel<<<(LL * DP * DP) / 256, 256, 0, stream>>>(W, WT);

    // ---- layers (l=0: embedding computed inside gemm A-staging; l>0: BN+relu
    //       of layer l-1 folded into gemm A-staging; BN stats fused into agg) ----
    for (int l = 0; l < LL; ++l) {
        gemm_kernel<<<dim3(391, 2), 256, 0, stream>>>(
            AH, WT + (size_t)l * DP * DP, HWb, NN, SCALE, SHIFT,
            x, emb1, emb2, l == 0 ? 2 : 1);
        agg_kernel<<<AGGB, 256, 0, stream>>>(HWb, PTR, SRC, SV + (size_t)l * NN, AH, PART);
        finalize1_kernel<<<64, 256, 0, stream>>>(PART, PART2);
        finalize_kernel<<<1, 320, 0, stream>>>(PART2, gamma + l * DD, beta + l * DD, SCALE, SHIFT);
    }

    // ---- head (BN affine of last layer applied after pooling — linear) ----
    pool_kernel<<<GG / 4, 256, 0, stream>>>(AH, batch, SCALE, SHIFT, HG);
    feat_kernel<<<GG, 256, 0, stream>>>(HG, fw, fb, HFEAT, out0);
    mlp_kernel<<<GG, 256, 0, stream>>>(HFEAT, w1, b1, w2, b2, out1);
}

// Round 14
// 1001.411 us; speedup vs baseline: 1.1636x; 1.1636x over previous
//
#include <hip/hip_runtime.h>
#include <hip/hip_bf16.h>

// Problem constants
#define NN 50000
#define EE 800000
#define GG 1024
#define DD 300
#define DP 320        // padded feature dim (multiple of 32 for MFMA K)
#define LL 5
#define FEAT 256

#define AGGB 3136     // agg blocks: 16 nodes/block (4/wave); 3136 = 64*49

typedef __bf16 bf16x8 __attribute__((ext_vector_type(8)));
typedef float  f32x4  __attribute__((ext_vector_type(4)));

#define AS1 __attribute__((address_space(1)))
#define AS3 __attribute__((address_space(3)))

// async global->LDS, 16B per lane; LDS dst must be wave-uniform base + lane*16
__device__ __forceinline__ void dma16(const __hip_bfloat16* g, __hip_bfloat16* l) {
    auto gp = reinterpret_cast<const AS1 char*>(reinterpret_cast<uintptr_t>(g));
    auto lp = reinterpret_cast<AS3 char*>((unsigned int)(uintptr_t)l);
    __builtin_amdgcn_global_load_lds(gp, lp, 16, 0, 0);
}

// unpack 8 bf16 (int4) and add into 8 f32 accumulators (pool kernel)
__device__ __forceinline__ void addbf8(float* a, int4 q) {
    unsigned int u;
    u = (unsigned int)q.x;
    a[0] += __uint_as_float(u << 16); a[1] += __uint_as_float(u & 0xFFFF0000u);
    u = (unsigned int)q.y;
    a[2] += __uint_as_float(u << 16); a[3] += __uint_as_float(u & 0xFFFF0000u);
    u = (unsigned int)q.z;
    a[4] += __uint_as_float(u << 16); a[5] += __uint_as_float(u & 0xFFFF0000u);
    u = (unsigned int)q.w;
    a[6] += __uint_as_float(u << 16); a[7] += __uint_as_float(u & 0xFFFF0000u);
}

// ---------------------------------------------------------------------------
__global__ void hist_kernel(const int* __restrict__ ei, int* __restrict__ deg) {
    int e = blockIdx.x * 256 + threadIdx.x;
    atomicAdd(&deg[ei[EE + e]], 1);
}

__global__ void scan1_kernel(const int* __restrict__ deg, int* __restrict__ ptr,
                             int* __restrict__ bsum) {
    __shared__ int buf[256];
    int tid = threadIdx.x;
    int i = blockIdx.x * 256 + tid;
    int v = (i < NN) ? deg[i] : 0;
    buf[tid] = v; __syncthreads();
    for (int off = 1; off < 256; off <<= 1) {
        int t = (tid >= off) ? buf[tid - off] : 0;
        __syncthreads();
        buf[tid] += t;
        __syncthreads();
    }
    if (i < NN) ptr[i + 1] = buf[tid];     // inclusive within block
    if (tid == 255) bsum[blockIdx.x] = buf[255];
}

__global__ void scan2_kernel(int* __restrict__ bsum) {   // 196 block sums -> exclusive
    __shared__ int buf[256];
    int tid = threadIdx.x;
    int v = (tid < 196) ? bsum[tid] : 0;
    buf[tid] = v; __syncthreads();
    for (int off = 1; off < 256; off <<= 1) {
        int t = (tid >= off) ? buf[tid - off] : 0;
        __syncthreads();
        buf[tid] += t;
        __syncthreads();
    }
    if (tid < 196) bsum[tid] = buf[tid] - v;  // exclusive
}

__global__ void scan3_kernel(int* __restrict__ ptr, const int* __restrict__ bsum) {
    int i = blockIdx.x * 256 + threadIdx.x;
    if (i < NN) ptr[i + 1] += bsum[blockIdx.x];
    if (i == 0) ptr[0] = 0;
}

// ---------------------------------------------------------------------------
// scatter edges into CSC src list; attrs packed into spare bits (r<65536).
__global__ void scatter_kernel(const int* __restrict__ ei, const int* __restrict__ ea,
                               const int* __restrict__ ptr, int* __restrict__ cur,
                               int* __restrict__ srcout) {
    int e = blockIdx.x * 256 + threadIdx.x;
    int r = ei[e], c = ei[EE + e];
    int a0 = ea[e * 2 + 0], a1 = ea[e * 2 + 1];
    int pos = ptr[c] + atomicAdd(&cur[c], 1);
    srcout[pos] = r | (a0 << 16) | (a1 << 18);
}

// ---------------------------------------------------------------------------
// per-node per-layer edge-scalar sums, no atomics
__global__ void sv_kernel(const int* __restrict__ ptr, const int* __restrict__ src,
                          const float* __restrict__ e1, const float* __restrict__ e2,
                          float* __restrict__ SV) {
    int v = blockIdx.x * 256 + threadIdx.x;
    if (v >= NN) return;
    float c00 = 0.f, c01 = 0.f, c02 = 0.f, c10 = 0.f, c11 = 0.f, c12 = 0.f;
    int beg = ptr[v], end = ptr[v + 1];
    for (int i = beg; i < end; ++i) {
        int p = src[i];
        int e0 = (p >> 16) & 3, ev = (p >> 18) & 3;
        c00 += (e0 == 0); c01 += (e0 == 1); c02 += (e0 == 2);
        c10 += (ev == 0); c11 += (ev == 1); c12 += (ev == 2);
    }
#pragma unroll
    for (int l = 0; l < LL; ++l) {
        float s = c00 * e1[l * 5 + 0] + c01 * e1[l * 5 + 1] + c02 * e1[l * 5 + 2]
                + c10 * e2[l * 3 + 0] + c11 * e2[l * 3 + 1] + c12 * e2[l * 3 + 2];
        SV[l * NN + v] = s;
    }
}

// ---------------------------------------------------------------------------
// repack W[l] (k,n row-major, 300x300 f32) into TILED+SWIZZLED bf16 WT for BK=64
// (r10-proven layout): [l][ntile(2)][ktile(5)][nn(160) x 8 pu x 8 el]; the 16B
// unit at (nn,pu) holds logical k-unit u = pu ^ (nn&7), k = ktile*64 + u*8..+7.
__global__ void repack_kernel(const float* __restrict__ W,
                              __hip_bfloat16* __restrict__ WT) {
    int idx = blockIdx.x * 256 + threadIdx.x;       // < LL*DP*DP
    int l = idx / (DP * DP);
    int r = idx - l * DP * DP;
    int ntile = r / 51200; r -= ntile * 51200;
    int ktile = r / 10240; r -= ktile * 10240;
    int nn = r >> 6; r &= 63;
    int pu = r >> 3; int e = r & 7;
    int u = pu ^ (nn & 7);                 // logical k-unit stored at this slot
    int n = ntile * 160 + nn;
    int k = ktile * 64 + u * 8 + e;
    float v = 0.f;
    if (n < DD && k < DD) v = W[l * DD * DD + k * DD + n];
    WT[idx] = __float2bfloat16(v);
}

// ---------------------------------------------------------------------------
// GEMM v5: C[M x 320] = act(A) @ B. BK=64, grid (391,2). B barriered DMA (r10);
// A fragments load GLOBAL->REGISTER directly (no As LDS round-trip; LDS halved
// to 21.5 KB). mode==1: BN+relu fold in registers; mode==2: on-the-fly embedding.
// Epilogue: LDS-staged coalesced 16B C stores (r10).
__global__ __launch_bounds__(256) void gemm_kernel(
        const __hip_bfloat16* __restrict__ A, const __hip_bfloat16* __restrict__ BT,
        __hip_bfloat16* __restrict__ C, int M,
        const float* __restrict__ scale, const float* __restrict__ shift,
        const int* __restrict__ x, const float* __restrict__ emb1,
        const float* __restrict__ emb2, int mode) {
    // LDS pool: Bs 160*64*2 = 20480 B; epilogue reuses as Cs[64][168] = 21504 B
    __shared__ __align__(16) char smem[21504];
    __hip_bfloat16* Bs = reinterpret_cast<__hip_bfloat16*>(smem);
    __hip_bfloat16* Cs = reinterpret_cast<__hip_bfloat16*>(smem);
    int tid = threadIdx.x;
    int m0 = blockIdx.x * 128;
    int wave = tid >> 6, lane = tid & 63;
    int wm = (wave >> 1) * 64, wn = (wave & 1) * 80;
    int fm = lane & 15, fu = lane >> 4;     // k-unit 0..3 within a 32-k half

    f32x4 acc[4][5];
#pragma unroll
    for (int i = 0; i < 4; ++i)
#pragma unroll
        for (int j = 0; j < 5; ++j) acc[i][j] = (f32x4){0.f, 0.f, 0.f, 0.f};

    const __hip_bfloat16* btile0 = BT + (size_t)blockIdx.y * 51200;

    for (int k0 = 0; k0 < DP; k0 += 64) {
        __syncthreads();               // prev-iter Bs reads complete
        // B tile: 1280 x 16B units, async DMA straight to LDS
        const __hip_bfloat16* bt = btile0 + (k0 >> 6) * 10240;
#pragma unroll
        for (int i = 0; i < 5; ++i)
            dma16(bt + (size_t)(tid + i * 256) * 8, Bs + (tid + i * 256) * 8);
        // A fragments: global -> registers (8 x dwordx4 per lane per iter)
        int4 af[2][4];
#pragma unroll
        for (int h = 0; h < 2; ++h) {
#pragma unroll
            for (int mt = 0; mt < 4; ++mt) {
                int row = m0 + wm + mt * 16 + fm;
                int kb = k0 + h * 32 + fu * 8;
                int4 val = make_int4(0, 0, 0, 0);
                if (row < M) {
                    if (mode == 2) {
                        int i0 = x[row * 2 + 0], i1 = x[row * 2 + 1];
                        union { int4 i4; __hip_bfloat16 hh[8]; } o;
#pragma unroll
                        for (int j4 = 0; j4 < 2; ++j4) {
                            int kk = kb + j4 * 4;
                            if (kk + 3 < DD) {   // emb rows & kk are 16B-aligned
                                float4 ea = *reinterpret_cast<const float4*>(emb1 + i0 * DD + kk);
                                float4 eb = *reinterpret_cast<const float4*>(emb2 + i1 * DD + kk);
                                o.hh[j4 * 4 + 0] = __float2bfloat16(ea.x + eb.x);
                                o.hh[j4 * 4 + 1] = __float2bfloat16(ea.y + eb.y);
                                o.hh[j4 * 4 + 2] = __float2bfloat16(ea.z + eb.z);
                                o.hh[j4 * 4 + 3] = __float2bfloat16(ea.w + eb.w);
                            } else {
#pragma unroll
                                for (int j = 0; j < 4; ++j) {
                                    int k = kk + j;
                                    float v = (k < DD) ? emb1[i0 * DD + k] + emb2[i1 * DD + k]
                                                       : 0.f;
                                    o.hh[j4 * 4 + j] = __float2bfloat16(v);
                                }
                            }
                        }
                        val = o.i4;
                    } else {
                        val = *reinterpret_cast<const int4*>(A + (size_t)row * DP + kb);
                        if (mode == 1) {
                            __hip_bfloat16* hh = reinterpret_cast<__hip_bfloat16*>(&val);
#pragma unroll
                            for (int j = 0; j < 8; ++j) {
                                float f = fmaf(__bfloat162float(hh[j]), scale[kb + j],
                                               shift[kb + j]);
                                hh[j] = __float2bfloat16(fmaxf(f, 0.f));
                            }
                        }
                    }
                }
                af[h][mt] = val;
            }
        }
        __syncthreads();   // vmcnt(0) drain before barrier -> Bs + af ready
#pragma unroll
        for (int h = 0; h < 2; ++h) {
            bf16x8 bfr[5];
#pragma unroll
            for (int nt = 0; nt < 5; ++nt) {
                int n = wn + nt * 16 + fm;
                int pu = (h * 4 + fu) ^ (n & 7);
                bfr[nt] = *reinterpret_cast<const bf16x8*>(Bs + n * 64 + pu * 8);
            }
#pragma unroll
            for (int mt = 0; mt < 4; ++mt)
#pragma unroll
                for (int nt = 0; nt < 5; ++nt)
                    acc[mt][nt] = __builtin_amdgcn_mfma_f32_16x16x32_bf16(
                        *reinterpret_cast<bf16x8*>(&af[h][mt]), bfr[nt],
                        acc[mt][nt], 0, 0, 0);
        }
    }
    // epilogue via LDS: C/D layout col=lane&15, row=(lane>>4)*4+reg [m89-verified].
    int n0 = blockIdx.y * 160;
    int cc = lane & 15, cr = (lane >> 4) * 4;
#pragma unroll
    for (int h = 0; h < 2; ++h) {
        __syncthreads();
        if ((wave >> 1) == h) {
#pragma unroll
            for (int mt = 0; mt < 4; ++mt)
#pragma unroll
                for (int nt = 0; nt < 5; ++nt)
#pragma unroll
                    for (int r = 0; r < 4; ++r)
                        Cs[(mt * 16 + cr + r) * 168 + wn + nt * 16 + cc] =
                            __float2bfloat16(acc[mt][nt][r]);
        }
        __syncthreads();
        // 64 rows x 160 cols = 1280 16B units; 5 per thread, coalesced stores
#pragma unroll
        for (int u = tid; u < 1280; u += 256) {
            int r = u / 20, c16 = u % 20;
            int row = m0 + h * 64 + r;
            if (row < M)
                *reinterpret_cast<int4*>(C + (size_t)row * DP + n0 + c16 * 8) =
                    *reinterpret_cast<const int4*>(Cs + r * 168 + c16 * 8);
        }
    }
}

// ---------------------------------------------------------------------------
// aggregation + fused BN stats (r12-exact, the proven plateau shape):
// AGGB blocks x 4 waves; each wave processes 4 consecutive nodes (8B+2B loads,
// 4-wide unroll, 4 accumulator sets). Lane partials (sum/sumsq of its 5 owned
// dims) LDS-reduced to part[block][640] ([0..319]=sum, [320..639]=sumsq).
__global__ __launch_bounds__(256) void agg_kernel(
        const __hip_bfloat16* __restrict__ HW,
        const int* __restrict__ ptr, const int* __restrict__ src,
        const float* __restrict__ SVl, __hip_bfloat16* __restrict__ AH,
        float* __restrict__ part) {
    int w = threadIdx.x >> 6;
    int lane = threadIdx.x & 63;
    float sx = 0.f, sy = 0.f, sz = 0.f, sw = 0.f, st = 0.f;
    float qx = 0.f, qy = 0.f, qz = 0.f, qw = 0.f, qt = 0.f;

#pragma unroll
    for (int k = 0; k < 4; ++k) {
        int v = blockIdx.x * 16 + w * 4 + k;
        if (v >= NN) break;
        int beg = ptr[v], end = ptr[v + 1];
        const __hip_bfloat16* rv = HW + (size_t)v * DP;
        ushort4 qs = *reinterpret_cast<const ushort4*>(rv + 4 * lane);
        unsigned int ts = reinterpret_cast<const unsigned short*>(rv)[256 + lane];
        float A0x = __uint_as_float((unsigned int)qs.x << 16);
        float A0y = __uint_as_float((unsigned int)qs.y << 16);
        float A0z = __uint_as_float((unsigned int)qs.z << 16);
        float A0w = __uint_as_float((unsigned int)qs.w << 16);
        float A0t = __uint_as_float(ts << 16);
        float A1x = 0.f, A1y = 0.f, A1z = 0.f, A1w = 0.f, A1t = 0.f;
        float A2x = 0.f, A2y = 0.f, A2z = 0.f, A2w = 0.f, A2t = 0.f;
        float A3x = 0.f, A3y = 0.f, A3z = 0.f, A3w = 0.f, A3t = 0.f;
        int i = beg;
        for (; i < end && (i & 3); ++i) {
            int s0 = src[i] & 0xFFFF;
            const __hip_bfloat16* r0 = HW + (size_t)s0 * DP;
            ushort4 q0 = *reinterpret_cast<const ushort4*>(r0 + 4 * lane);
            unsigned int t0 = reinterpret_cast<const unsigned short*>(r0)[256 + lane];
            A0x += __uint_as_float((unsigned int)q0.x << 16);
            A0y += __uint_as_float((unsigned int)q0.y << 16);
            A0z += __uint_as_float((unsigned int)q0.z << 16);
            A0w += __uint_as_float((unsigned int)q0.w << 16);
            A0t += __uint_as_float(t0 << 16);
        }
        for (; i + 4 <= end; i += 4) {
            int4 s4 = *reinterpret_cast<const int4*>(src + i);
            int s0 = s4.x & 0xFFFF, s1 = s4.y & 0xFFFF;
            int s2 = s4.z & 0xFFFF, s3 = s4.w & 0xFFFF;
            const __hip_bfloat16* r0 = HW + (size_t)s0 * DP;
            const __hip_bfloat16* r1 = HW + (size_t)s1 * DP;
            const __hip_bfloat16* r2 = HW + (size_t)s2 * DP;
            const __hip_bfloat16* r3 = HW + (size_t)s3 * DP;
            ushort4 q0 = *reinterpret_cast<const ushort4*>(r0 + 4 * lane);
            ushort4 q1 = *reinterpret_cast<const ushort4*>(r1 + 4 * lane);
            ushort4 q2 = *reinterpret_cast<const ushort4*>(r2 + 4 * lane);
            ushort4 q3 = *reinterpret_cast<const ushort4*>(r3 + 4 * lane);
            unsigned int t0 = reinterpret_cast<const unsigned short*>(r0)[256 + lane];
            unsigned int t1 = reinterpret_cast<const unsigned short*>(r1)[256 + lane];
            unsigned int t2 = reinterpret_cast<const unsigned short*>(r2)[256 + lane];
            unsigned int t3 = reinterpret_cast<const unsigned short*>(r3)[256 + lane];
            A0x += __uint_as_float((unsigned int)q0.x << 16);
            A0y += __uint_as_float((unsigned int)q0.y << 16);
            A0z += __uint_as_float((unsigned int)q0.z << 16);
            A0w += __uint_as_float((unsigned int)q0.w << 16);
            A0t += __uint_as_float(t0 << 16);
            A1x += __uint_as_float((unsigned int)q1.x << 16);
            A1y += __uint_as_float((unsigned int)q1.y << 16);
            A1z += __uint_as_float((unsigned int)q1.z << 16);
            A1w += __uint_as_float((unsigned int)q1.w << 16);
            A1t += __uint_as_float(t1 << 16);
            A2x += __uint_as_float((unsigned int)q2.x << 16);
            A2y += __uint_as_float((unsigned int)q2.y << 16);
            A2z += __uint_as_float((unsigned int)q2.z << 16);
            A2w += __uint_as_float((unsigned int)q2.w << 16);
            A2t += __uint_as_float(t2 << 16);
            A3x += __uint_as_float((unsigned int)q3.x << 16);
            A3y += __uint_as_float((unsigned int)q3.y << 16);
            A3z += __uint_as_float((unsigned int)q3.z << 16);
            A3w += __uint_as_float((unsigned int)q3.w << 16);
            A3t += __uint_as_float(t3 << 16);
        }
        for (; i < end; ++i) {
            int s0 = src[i] & 0xFFFF;
            const __hip_bfloat16* r0 = HW + (size_t)s0 * DP;
            ushort4 q0 = *reinterpret_cast<const ushort4*>(r0 + 4 * lane);
            unsigned int t0 = reinterpret_cast<const unsigned short*>(r0)[256 + lane];
            A0x += __uint_as_float((unsigned int)q0.x << 16);
            A0y += __uint_as_float((unsigned int)q0.y << 16);
            A0z += __uint_as_float((unsigned int)q0.z << 16);
            A0w += __uint_as_float((unsigned int)q0.w << 16);
            A0t += __uint_as_float(t0 << 16);
        }
        float sv = SVl[v];
        float rx = A0x + A1x + A2x + A3x + sv;
        float ry = A0y + A1y + A2y + A3y + sv;
        float rz = A0z + A1z + A2z + A3z + sv;
        float rw = A0w + A1w + A2w + A3w + sv;
        float rt = A0t + A1t + A2t + A3t + sv;
        sx += rx; qx = fmaf(rx, rx, qx);
        sy += ry; qy = fmaf(ry, ry, qy);
        sz += rz; qz = fmaf(rz, rz, qz);
        sw += rw; qw = fmaf(rw, rw, qw);
        st += rt; qt = fmaf(rt, rt, qt);
        __hip_bfloat16* out = AH + (size_t)v * DP;
        union { ushort4 u; __hip_bfloat16 h[4]; } o;
        o.h[0] = __float2bfloat16(rx); o.h[1] = __float2bfloat16(ry);
        o.h[2] = __float2bfloat16(rz); o.h[3] = __float2bfloat16(rw);
        *reinterpret_cast<ushort4*>(out + 4 * lane) = o.u;
        out[256 + lane] = __float2bfloat16(lane < 44 ? rt : 0.f);  // 300..319 -> 0
    }
    // reduce 4 waves -> per-block partials
    __shared__ float red[4 * 640];    // 10.24 KB
    float* rw_ = red + w * 640;
    rw_[4 * lane + 0] = sx; rw_[4 * lane + 1] = sy;
    rw_[4 * lane + 2] = sz; rw_[4 * lane + 3] = sw;
    rw_[256 + lane] = (lane < 44) ? st : 0.f;
    rw_[320 + 4 * lane + 0] = qx; rw_[320 + 4 * lane + 1] = qy;
    rw_[320 + 4 * lane + 2] = qz; rw_[320 + 4 * lane + 3] = qw;
    rw_[320 + 256 + lane] = (lane < 44) ? qt : 0.f;
    __syncthreads();
    for (int i = threadIdx.x; i < 640; i += 256)
        part[(size_t)blockIdx.x * 640 + i] =
            red[i] + red[640 + i] + red[1280 + i] + red[1920 + i];
}

// reduce AGGB partials -> 64 partials  (AGGB = 64*49)
__global__ void finalize1_kernel(const float* __restrict__ part, float* __restrict__ part2) {
    int b = blockIdx.x;                 // 0..63
    const int K = AGGB / 64;            // 49
    for (int i = threadIdx.x; i < 640; i += 256) {
        float acc = 0.f;
        for (int k = 0; k < K; ++k)
            acc += part[(size_t)(b * K + k) * 640 + i];
        part2[b * 640 + i] = acc;
    }
}

// reduce 64 partials; writes scale/shift for ALL 320 dims (pad dims 0/0)
__global__ void finalize_kernel(const float* __restrict__ part2,
                                const float* __restrict__ gamma_l,
                                const float* __restrict__ beta_l,
                                float* __restrict__ scale, float* __restrict__ shift) {
    int d = threadIdx.x;                 // block of 320
    float sc = 0.f, sh = 0.f;
    if (d < DD) {
        float s = 0.f, q = 0.f;
        for (int b = 0; b < 64; ++b) {
            s += part2[b * 640 + d];
            q += part2[b * 640 + 320 + d];
        }
        const float invN = 1.0f / (float)NN;
        float mean = s * invN;
        float var = q * invN - mean * mean;
        var = fmaxf(var, 0.f);                      // guard fp32 cancellation
        float rs = rsqrtf(var + 1e-5f);
        sc = rs * gamma_l[d];
        sh = beta_l[d] - mean * sc;
    }
    scale[d] = sc;
    shift[d] = sh;
}

// ---------------------------------------------------------------------------
__device__ __forceinline__ int lower_bound_dev(const int* b, int n, int key) {
    int lo = 0, hi = n;
    while (lo < hi) { int mid = (lo + hi) >> 1; if (b[mid] < key) lo = mid + 1; else hi = mid; }
    return lo;
}

// mean pool per graph over raw h_pre, then the last layer's BN affine applied
// after pooling (linear). One wave per graph; 16B loads on lanes 0..39.
__global__ void pool_kernel(const __hip_bfloat16* __restrict__ A, const int* __restrict__ batch,
                            const float* __restrict__ scale, const float* __restrict__ shift,
                            float* __restrict__ HG) {
    int g = blockIdx.x * 4 + (threadIdx.x >> 6);
    int lane = threadIdx.x & 63;
    bool act = lane < 40;
    int lo = lower_bound_dev(batch, NN, g);
    int hi = lower_bound_dev(batch, NN, g + 1);
    const int4 z4 = make_int4(0, 0, 0, 0);
    float a[8];
#pragma unroll
    for (int j = 0; j < 8; ++j) a[j] = 0.f;
    for (int v = lo; v < hi; ++v) {
        int4 q = act ? *reinterpret_cast<const int4*>(A + (size_t)v * DP + 8 * lane) : z4;
        addbf8(a, q);
    }
    if (act) {
        int cnt = hi - lo;
        float inv = 1.0f / (float)(cnt > 0 ? cnt : 1);
        float* out = HG + (size_t)g * DP;
#pragma unroll
        for (int j = 0; j < 8; ++j) {
            int d = 8 * lane + j;
            out[d] = fmaf(a[j] * inv, scale[d], shift[d]);  // pad dims: 0/0 -> 0
        }
    }
}

// h_feat = hg @ feat_w + feat_b   (one block per graph), f32 out
__global__ void feat_kernel(const float* __restrict__ HG,
                            const float* __restrict__ fw,
                            const float* __restrict__ fb,
                            float* __restrict__ HFEAT, float* __restrict__ out0) {
    __shared__ float hgs[DD];
    int g = blockIdx.x, tid = threadIdx.x;
    for (int i = tid; i < DD; i += 256) hgs[i] = HG[(size_t)g * DP + i];
    __syncthreads();
    float acc = fb[tid];
#pragma unroll 4
    for (int k = 0; k < DD; ++k)
        acc = fmaf(hgs[k], fw[k * FEAT + tid], acc);
    HFEAT[g * FEAT + tid] = acc;
    out0[g * FEAT + tid] = acc;
}

// out = relu(h_feat @ w1 + b1) @ w2 + b2   (one block per graph), f32 out
__global__ void mlp_kernel(const float* __restrict__ HFEAT,
                           const float* __restrict__ w1, const float* __restrict__ b1,
                           const float* __restrict__ w2, const float* __restrict__ b2,
                           float* __restrict__ out1) {
    __shared__ float hf[FEAT], t[FEAT];
    int g = blockIdx.x, tid = threadIdx.x;
    hf[tid] = HFEAT[g * FEAT + tid];
    __syncthreads();
    float acc = b1[tid];
#pragma unroll 4
    for (int k = 0; k < FEAT; ++k)
        acc = fmaf(hf[k], w1[k * FEAT + tid], acc);
    t[tid] = fmaxf(acc, 0.f);
    __syncthreads();
    if (tid < FEAT / 2) {
        float acc2 = b2[tid];
#pragma unroll 4
        for (int k = 0; k < FEAT; ++k)
            acc2 = fmaf(t[k], w2[k * (FEAT / 2) + tid], acc2);
        out1[g * (FEAT / 2) + tid] = acc2;
    }
}

// ---------------------------------------------------------------------------
extern "C" void kernel_launch(void* const* d_in, const int* in_sizes, int n_in,
                              void* d_out, int out_size, void* d_ws, size_t ws_size,
                              hipStream_t stream) {
    const int* x     = (const int*)d_in[0];
    const int* ei    = (const int*)d_in[1];
    const int* ea    = (const int*)d_in[2];
    const int* batch = (const int*)d_in[3];
    const float* emb1  = (const float*)d_in[4];
    const float* emb2  = (const float*)d_in[5];
    const float* W     = (const float*)d_in[6];
    // d_in[7] = b[l]: per-dim constant, cancelled by BatchNorm -> unused
    const float* e1    = (const float*)d_in[8];
    const float* e2    = (const float*)d_in[9];
    const float* gamma = (const float*)d_in[10];
    const float* beta  = (const float*)d_in[11];
    const float* fw    = (const float*)d_in[12];
    const float* fb    = (const float*)d_in[13];
    const float* w1    = (const float*)d_in[14];
    const float* b1    = (const float*)d_in[15];
    const float* w2    = (const float*)d_in[16];
    const float* b2    = (const float*)d_in[17];

    // workspace carve (~80 MB total; small control buffers FIRST)
    char* base = (char*)d_ws;
    size_t off = 0;
    auto carve = [&](size_t bytes) -> void* {
        void* p = base + off;
        off = (off + bytes + 255) & ~(size_t)255;
        return p;
    };
    int*            PTR   = (int*)carve((size_t)(NN + 1) * 4);
    int*            CUR   = (int*)carve((size_t)NN * 4);
    int*            SRC   = (int*)carve((size_t)EE * 4);
    float*          SV    = (float*)carve((size_t)LL * NN * 4);
    int*            BSUM  = (int*)carve(256 * 4);
    float*          PART  = (float*)carve((size_t)AGGB * 640 * 4);
    float*          PART2 = (float*)carve((size_t)64 * 640 * 4);
    float*          SCALE = (float*)carve(DP * 4);
    float*          SHIFT = (float*)carve(DP * 4);
    float*          HG    = (float*)carve((size_t)GG * DP * 4);
    float*          HFEAT = (float*)carve((size_t)GG * FEAT * 4);
    __hip_bfloat16* WT    = (__hip_bfloat16*)carve((size_t)LL * DP * DP * 2);
    __hip_bfloat16* AH    = (__hip_bfloat16*)carve((size_t)NN * DP * 2);  // h_pre ping
    __hip_bfloat16* HWb   = (__hip_bfloat16*)carve((size_t)NN * DP * 2);  // gemm out pong

    float* out0 = (float*)d_out;                 // h_feat [G,256] f32
    float* out1 = (float*)d_out + GG * FEAT;     // out    [G,128] f32

    // ---- preprocess (ws is re-poisoned before every call) ----
    hipMemsetAsync(CUR, 0, (size_t)NN * 4, stream);
    hist_kernel<<<EE / 256, 256, 0, stream>>>(ei, CUR);
    scan1_kernel<<<196, 256, 0, stream>>>(CUR, PTR, BSUM);
    scan2_kernel<<<1, 256, 0, stream>>>(BSUM);
    scan3_kernel<<<196, 256, 0, stream>>>(PTR, BSUM);
    hipMemsetAsync(CUR, 0, (size_t)NN * 4, stream);
    scatter_kernel<<<EE / 256, 256, 0, stream>>>(ei, ea, PTR, CUR, SRC);
    sv_kernel<<<196, 256, 0, stream>>>(PTR, SRC, e1, e2, SV);
    repack_kernel<<<(LL * DP * DP) / 256, 256, 0, stream>>>(W, WT);

    // ---- layers (l=0: embedding computed inside gemm A-loads; l>0: BN+relu
    //       of layer l-1 folded into gemm A-loads; BN stats fused into agg) ----
    for (int l = 0; l < LL; ++l) {
        gemm_kernel<<<dim3(391, 2), 256, 0, stream>>>(
            AH, WT + (size_t)l * DP * DP, HWb, NN, SCALE, SHIFT,
            x, emb1, emb2, l == 0 ? 2 : 1);
        agg_kernel<<<AGGB, 256, 0, stream>>>(HWb, PTR, SRC, SV + (size_t)l * NN, AH, PART);
        finalize1_kernel<<<64, 256, 0, stream>>>(PART, PART2);
        finalize_kernel<<<1, 320, 0, stream>>>(PART2, gamma + l * DD, beta + l * DD, SCALE, SHIFT);
    }

    // ---- head (BN affine of last layer applied after pooling — linear) ----
    pool_kernel<<<GG / 4, 256, 0, stream>>>(AH, batch, SCALE, SHIFT, HG);
    feat_kernel<<<GG, 256, 0, stream>>>(HG, fw, fb, HFEAT, out0);
    mlp_kernel<<<GG, 256, 0, stream>>>(HFEAT, w1, b1, w2, b2, out1);
}

// Round 15
// 907.971 us; speedup vs baseline: 1.2834x; 1.1029x over previous
//
#include <hip/hip_runtime.h>
#include <hip/hip_bf16.h>

// Problem constants
#define NN 50000
#define EE 800000
#define GG 1024
#define DD 300
#define DP 320        // padded feature dim (multiple of 32 for MFMA K)
#define LL 5
#define FEAT 256

#define AGGB 3136     // agg blocks: 16 nodes/block (4/wave); 3136 = 64*49

typedef __bf16 bf16x8 __attribute__((ext_vector_type(8)));
typedef float  f32x4  __attribute__((ext_vector_type(4)));

#define AS1 __attribute__((address_space(1)))
#define AS3 __attribute__((address_space(3)))

// async global->LDS, 16B per lane; LDS dst must be wave-uniform base + lane*16
__device__ __forceinline__ void dma16(const __hip_bfloat16* g, __hip_bfloat16* l) {
    auto gp = reinterpret_cast<const AS1 char*>(reinterpret_cast<uintptr_t>(g));
    auto lp = reinterpret_cast<AS3 char*>((unsigned int)(uintptr_t)l);
    __builtin_amdgcn_global_load_lds(gp, lp, 16, 0, 0);
}

// unpack 8 bf16 (int4) and add into 8 f32 accumulators (pool kernel)
__device__ __forceinline__ void addbf8(float* a, int4 q) {
    unsigned int u;
    u = (unsigned int)q.x;
    a[0] += __uint_as_float(u << 16); a[1] += __uint_as_float(u & 0xFFFF0000u);
    u = (unsigned int)q.y;
    a[2] += __uint_as_float(u << 16); a[3] += __uint_as_float(u & 0xFFFF0000u);
    u = (unsigned int)q.z;
    a[4] += __uint_as_float(u << 16); a[5] += __uint_as_float(u & 0xFFFF0000u);
    u = (unsigned int)q.w;
    a[6] += __uint_as_float(u << 16); a[7] += __uint_as_float(u & 0xFFFF0000u);
}

// ---------------------------------------------------------------------------
__global__ void hist_kernel(const int* __restrict__ ei, int* __restrict__ deg) {
    int e = blockIdx.x * 256 + threadIdx.x;
    atomicAdd(&deg[ei[EE + e]], 1);
}

__global__ void scan1_kernel(const int* __restrict__ deg, int* __restrict__ ptr,
                             int* __restrict__ bsum) {
    __shared__ int buf[256];
    int tid = threadIdx.x;
    int i = blockIdx.x * 256 + tid;
    int v = (i < NN) ? deg[i] : 0;
    buf[tid] = v; __syncthreads();
    for (int off = 1; off < 256; off <<= 1) {
        int t = (tid >= off) ? buf[tid - off] : 0;
        __syncthreads();
        buf[tid] += t;
        __syncthreads();
    }
    if (i < NN) ptr[i + 1] = buf[tid];     // inclusive within block
    if (tid == 255) bsum[blockIdx.x] = buf[255];
}

__global__ void scan2_kernel(int* __restrict__ bsum) {   // 196 block sums -> exclusive
    __shared__ int buf[256];
    int tid = threadIdx.x;
    int v = (tid < 196) ? bsum[tid] : 0;
    buf[tid] = v; __syncthreads();
    for (int off = 1; off < 256; off <<= 1) {
        int t = (tid >= off) ? buf[tid - off] : 0;
        __syncthreads();
        buf[tid] += t;
        __syncthreads();
    }
    if (tid < 196) bsum[tid] = buf[tid] - v;  // exclusive
}

__global__ void scan3_kernel(int* __restrict__ ptr, const int* __restrict__ bsum) {
    int i = blockIdx.x * 256 + threadIdx.x;
    if (i < NN) ptr[i + 1] += bsum[blockIdx.x];
    if (i == 0) ptr[0] = 0;
}

// ---------------------------------------------------------------------------
// scatter edges into CSC src list; attrs packed into spare bits (r<65536).
__global__ void scatter_kernel(const int* __restrict__ ei, const int* __restrict__ ea,
                               const int* __restrict__ ptr, int* __restrict__ cur,
                               int* __restrict__ srcout) {
    int e = blockIdx.x * 256 + threadIdx.x;
    int r = ei[e], c = ei[EE + e];
    int a0 = ea[e * 2 + 0], a1 = ea[e * 2 + 1];
    int pos = ptr[c] + atomicAdd(&cur[c], 1);
    srcout[pos] = r | (a0 << 16) | (a1 << 18);
}

// ---------------------------------------------------------------------------
// per-node per-layer edge-scalar sums, no atomics
__global__ void sv_kernel(const int* __restrict__ ptr, const int* __restrict__ src,
                          const float* __restrict__ e1, const float* __restrict__ e2,
                          float* __restrict__ SV) {
    int v = blockIdx.x * 256 + threadIdx.x;
    if (v >= NN) return;
    float c00 = 0.f, c01 = 0.f, c02 = 0.f, c10 = 0.f, c11 = 0.f, c12 = 0.f;
    int beg = ptr[v], end = ptr[v + 1];
    for (int i = beg; i < end; ++i) {
        int p = src[i];
        int e0 = (p >> 16) & 3, ev = (p >> 18) & 3;
        c00 += (e0 == 0); c01 += (e0 == 1); c02 += (e0 == 2);
        c10 += (ev == 0); c11 += (ev == 1); c12 += (ev == 2);
    }
#pragma unroll
    for (int l = 0; l < LL; ++l) {
        float s = c00 * e1[l * 5 + 0] + c01 * e1[l * 5 + 1] + c02 * e1[l * 5 + 2]
                + c10 * e2[l * 3 + 0] + c11 * e2[l * 3 + 1] + c12 * e2[l * 3 + 2];
        SV[l * NN + v] = s;
    }
}

// ---------------------------------------------------------------------------
// repack W[l] (k,n row-major, 300x300 f32) into TILED+SWIZZLED bf16 WT for BK=64
// (r10-proven layout): [l][ntile(2)][ktile(5)][nn(160) x 8 pu x 8 el]; the 16B
// unit at (nn,pu) holds logical k-unit u = pu ^ (nn&7), k = ktile*64 + u*8..+7.
__global__ void repack_kernel(const float* __restrict__ W,
                              __hip_bfloat16* __restrict__ WT) {
    int idx = blockIdx.x * 256 + threadIdx.x;       // < LL*DP*DP
    int l = idx / (DP * DP);
    int r = idx - l * DP * DP;
    int ntile = r / 51200; r -= ntile * 51200;
    int ktile = r / 10240; r -= ktile * 10240;
    int nn = r >> 6; r &= 63;
    int pu = r >> 3; int e = r & 7;
    int u = pu ^ (nn & 7);                 // logical k-unit stored at this slot
    int n = ntile * 160 + nn;
    int k = ktile * 64 + u * 8 + e;
    float v = 0.f;
    if (n < DD && k < DD) v = W[l * DD * DD + k * DD + n];
    WT[idx] = __float2bfloat16(v);
}

// ---------------------------------------------------------------------------
// GEMM (r10/r12-proven structure): C[M x 320] = act(A) @ B. BK=64, grid (391,2).
// B pre-tiled/swizzled, staged via global_load_lds (16B DMA).
// mode==1: act(x) = relu(x*scale[k]+shift[k]) folded into A-staging.
// mode==2: A is the node EMBEDDING computed on the fly from x/emb1/emb2.
// Epilogue: LDS-staged coalesced 16B C stores.
__global__ __launch_bounds__(256) void gemm_kernel(
        const __hip_bfloat16* __restrict__ A, const __hip_bfloat16* __restrict__ BT,
        __hip_bfloat16* __restrict__ C, int M,
        const float* __restrict__ scale, const float* __restrict__ shift,
        const int* __restrict__ x, const float* __restrict__ emb1,
        const float* __restrict__ emb2, int mode) {
    // shared pool: As (128*72*2=18432) + Bs (160*64*2=20480) = 38912 B;
    // epilogue reuses it as 64 rows x stride 168 bf16 (= 21504 B).
    __shared__ __align__(16) char smem[38912];
    __hip_bfloat16* As = reinterpret_cast<__hip_bfloat16*>(smem);            // [128*72]
    __hip_bfloat16* Bs = reinterpret_cast<__hip_bfloat16*>(smem + 18432);    // [160*64]
    __hip_bfloat16* Cs = reinterpret_cast<__hip_bfloat16*>(smem);            // [64*168]
    int tid = threadIdx.x;
    int m0 = blockIdx.x * 128;
    int wave = tid >> 6, lane = tid & 63;
    int wm = (wave >> 1) * 64, wn = (wave & 1) * 80;
    int fm = lane & 15, fu = lane >> 4;     // k-unit 0..3 within a 32-k half

    f32x4 acc[4][5];
#pragma unroll
    for (int i = 0; i < 4; ++i)
#pragma unroll
        for (int j = 0; j < 5; ++j) acc[i][j] = (f32x4){0.f, 0.f, 0.f, 0.f};

    const __hip_bfloat16* btile0 = BT + (size_t)blockIdx.y * 51200;

    for (int k0 = 0; k0 < DP; k0 += 64) {
        __syncthreads();
        // B tile: 1280 x 16B units, async DMA straight to LDS
        const __hip_bfloat16* bt = btile0 + (k0 >> 6) * 10240;
#pragma unroll
        for (int i = 0; i < 5; ++i)
            dma16(bt + (size_t)(tid + i * 256) * 8, Bs + (tid + i * 256) * 8);
        // A tile: VGPR path (BN+relu fold or on-the-fly embedding), 1024 units
#pragma unroll
        for (int u = tid; u < 1024; u += 256) {
            int r = u >> 3, p = u & 7;
            int gr = m0 + r;
            int4 val = make_int4(0, 0, 0, 0);
            if (gr < M) {
                if (mode == 2) {
                    int i0 = x[gr * 2 + 0], i1 = x[gr * 2 + 1];
                    int kb = k0 + p * 8;
                    union { int4 i4; __hip_bfloat16 h[8]; } o;
#pragma unroll
                    for (int j4 = 0; j4 < 2; ++j4) {
                        int kk = kb + j4 * 4;
                        if (kk + 3 < DD) {   // i0*300*4 and kk*4 are 16B-aligned
                            float4 ea = *reinterpret_cast<const float4*>(emb1 + i0 * DD + kk);
                            float4 eb = *reinterpret_cast<const float4*>(emb2 + i1 * DD + kk);
                            o.h[j4 * 4 + 0] = __float2bfloat16(ea.x + eb.x);
                            o.h[j4 * 4 + 1] = __float2bfloat16(ea.y + eb.y);
                            o.h[j4 * 4 + 2] = __float2bfloat16(ea.z + eb.z);
                            o.h[j4 * 4 + 3] = __float2bfloat16(ea.w + eb.w);
                        } else {
#pragma unroll
                            for (int j = 0; j < 4; ++j) {
                                int k = kk + j;
                                float v = (k < DD) ? emb1[i0 * DD + k] + emb2[i1 * DD + k]
                                                   : 0.f;
                                o.h[j4 * 4 + j] = __float2bfloat16(v);
                            }
                        }
                    }
                    val = o.i4;
                } else {
                    val = *reinterpret_cast<const int4*>(A + (size_t)gr * DP + k0 + p * 8);
                    if (mode == 1) {
                        __hip_bfloat16* hh = reinterpret_cast<__hip_bfloat16*>(&val);
                        int kb = k0 + p * 8;
#pragma unroll
                        for (int j = 0; j < 8; ++j) {
                            float f = fmaf(__bfloat162float(hh[j]), scale[kb + j], shift[kb + j]);
                            hh[j] = __float2bfloat16(fmaxf(f, 0.f));
                        }
                    }
                }
            }
            *reinterpret_cast<int4*>(As + r * 72 + p * 8) = val;
        }
        __syncthreads();
#pragma unroll
        for (int h = 0; h < 2; ++h) {
            bf16x8 af[4], bfr[5];
#pragma unroll
            for (int mt = 0; mt < 4; ++mt)
                af[mt] = *reinterpret_cast<const bf16x8*>(
                    As + (wm + mt * 16 + fm) * 72 + h * 32 + fu * 8);
#pragma unroll
            for (int nt = 0; nt < 5; ++nt) {
                int n = wn + nt * 16 + fm;
                int pu = (h * 4 + fu) ^ (n & 7);
                bfr[nt] = *reinterpret_cast<const bf16x8*>(Bs + n * 64 + pu * 8);
            }
#pragma unroll
            for (int mt = 0; mt < 4; ++mt)
#pragma unroll
                for (int nt = 0; nt < 5; ++nt)
                    acc[mt][nt] = __builtin_amdgcn_mfma_f32_16x16x32_bf16(
                        af[mt], bfr[nt], acc[mt][nt], 0, 0, 0);
        }
    }
    // epilogue via LDS: C/D layout col=lane&15, row=(lane>>4)*4+reg [m89-verified].
    int n0 = blockIdx.y * 160;
    int cc = lane & 15, cr = (lane >> 4) * 4;
#pragma unroll
    for (int h = 0; h < 2; ++h) {
        __syncthreads();
        if ((wave >> 1) == h) {
#pragma unroll
            for (int mt = 0; mt < 4; ++mt)
#pragma unroll
                for (int nt = 0; nt < 5; ++nt)
#pragma unroll
                    for (int r = 0; r < 4; ++r)
                        Cs[(mt * 16 + cr + r) * 168 + wn + nt * 16 + cc] =
                            __float2bfloat16(acc[mt][nt][r]);
        }
        __syncthreads();
        // 64 rows x 160 cols = 1280 16B units; 5 per thread, coalesced stores
#pragma unroll
        for (int u = tid; u < 1280; u += 256) {
            int r = u / 20, c16 = u % 20;
            int row = m0 + h * 64 + r;
            if (row < M)
                *reinterpret_cast<int4*>(C + (size_t)row * DP + n0 + c16 * 8) =
                    *reinterpret_cast<const int4*>(Cs + r * 168 + c16 * 8);
        }
    }
}

// ---------------------------------------------------------------------------
// aggregation + fused BN stats (r12-exact, the proven plateau shape):
// AGGB blocks x 4 waves; each wave processes 4 consecutive nodes (8B+2B loads,
// 4-wide unroll, 4 accumulator sets). Lane partials (sum/sumsq of its 5 owned
// dims) LDS-reduced to part[block][640] ([0..319]=sum, [320..639]=sumsq).
__global__ __launch_bounds__(256) void agg_kernel(
        const __hip_bfloat16* __restrict__ HW,
        const int* __restrict__ ptr, const int* __restrict__ src,
        const float* __restrict__ SVl, __hip_bfloat16* __restrict__ AH,
        float* __restrict__ part) {
    int w = threadIdx.x >> 6;
    int lane = threadIdx.x & 63;
    float sx = 0.f, sy = 0.f, sz = 0.f, sw = 0.f, st = 0.f;
    float qx = 0.f, qy = 0.f, qz = 0.f, qw = 0.f, qt = 0.f;

#pragma unroll
    for (int k = 0; k < 4; ++k) {
        int v = blockIdx.x * 16 + w * 4 + k;
        if (v >= NN) break;
        int beg = ptr[v], end = ptr[v + 1];
        const __hip_bfloat16* rv = HW + (size_t)v * DP;
        ushort4 qs = *reinterpret_cast<const ushort4*>(rv + 4 * lane);
        unsigned int ts = reinterpret_cast<const unsigned short*>(rv)[256 + lane];
        float A0x = __uint_as_float((unsigned int)qs.x << 16);
        float A0y = __uint_as_float((unsigned int)qs.y << 16);
        float A0z = __uint_as_float((unsigned int)qs.z << 16);
        float A0w = __uint_as_float((unsigned int)qs.w << 16);
        float A0t = __uint_as_float(ts << 16);
        float A1x = 0.f, A1y = 0.f, A1z = 0.f, A1w = 0.f, A1t = 0.f;
        float A2x = 0.f, A2y = 0.f, A2z = 0.f, A2w = 0.f, A2t = 0.f;
        float A3x = 0.f, A3y = 0.f, A3z = 0.f, A3w = 0.f, A3t = 0.f;
        int i = beg;
        for (; i < end && (i & 3); ++i) {
            int s0 = src[i] & 0xFFFF;
            const __hip_bfloat16* r0 = HW + (size_t)s0 * DP;
            ushort4 q0 = *reinterpret_cast<const ushort4*>(r0 + 4 * lane);
            unsigned int t0 = reinterpret_cast<const unsigned short*>(r0)[256 + lane];
            A0x += __uint_as_float((unsigned int)q0.x << 16);
            A0y += __uint_as_float((unsigned int)q0.y << 16);
            A0z += __uint_as_float((unsigned int)q0.z << 16);
            A0w += __uint_as_float((unsigned int)q0.w << 16);
            A0t += __uint_as_float(t0 << 16);
        }
        for (; i + 4 <= end; i += 4) {
            int4 s4 = *reinterpret_cast<const int4*>(src + i);
            int s0 = s4.x & 0xFFFF, s1 = s4.y & 0xFFFF;
            int s2 = s4.z & 0xFFFF, s3 = s4.w & 0xFFFF;
            const __hip_bfloat16* r0 = HW + (size_t)s0 * DP;
            const __hip_bfloat16* r1 = HW + (size_t)s1 * DP;
            const __hip_bfloat16* r2 = HW + (size_t)s2 * DP;
            const __hip_bfloat16* r3 = HW + (size_t)s3 * DP;
            ushort4 q0 = *reinterpret_cast<const ushort4*>(r0 + 4 * lane);
            ushort4 q1 = *reinterpret_cast<const ushort4*>(r1 + 4 * lane);
            ushort4 q2 = *reinterpret_cast<const ushort4*>(r2 + 4 * lane);
            ushort4 q3 = *reinterpret_cast<const ushort4*>(r3 + 4 * lane);
            unsigned int t0 = reinterpret_cast<const unsigned short*>(r0)[256 + lane];
            unsigned int t1 = reinterpret_cast<const unsigned short*>(r1)[256 + lane];
            unsigned int t2 = reinterpret_cast<const unsigned short*>(r2)[256 + lane];
            unsigned int t3 = reinterpret_cast<const unsigned short*>(r3)[256 + lane];
            A0x += __uint_as_float((unsigned int)q0.x << 16);
            A0y += __uint_as_float((unsigned int)q0.y << 16);
            A0z += __uint_as_float((unsigned int)q0.z << 16);
            A0w += __uint_as_float((unsigned int)q0.w << 16);
            A0t += __uint_as_float(t0 << 16);
            A1x += __uint_as_float((unsigned int)q1.x << 16);
            A1y += __uint_as_float((unsigned int)q1.y << 16);
            A1z += __uint_as_float((unsigned int)q1.z << 16);
            A1w += __uint_as_float((unsigned int)q1.w << 16);
            A1t += __uint_as_float(t1 << 16);
            A2x += __uint_as_float((unsigned int)q2.x << 16);
            A2y += __uint_as_float((unsigned int)q2.y << 16);
            A2z += __uint_as_float((unsigned int)q2.z << 16);
            A2w += __uint_as_float((unsigned int)q2.w << 16);
            A2t += __uint_as_float(t2 << 16);
            A3x += __uint_as_float((unsigned int)q3.x << 16);
            A3y += __uint_as_float((unsigned int)q3.y << 16);
            A3z += __uint_as_float((unsigned int)q3.z << 16);
            A3w += __uint_as_float((unsigned int)q3.w << 16);
            A3t += __uint_as_float(t3 << 16);
        }
        for (; i < end; ++i) {
            int s0 = src[i] & 0xFFFF;
            const __hip_bfloat16* r0 = HW + (size_t)s0 * DP;
            ushort4 q0 = *reinterpret_cast<const ushort4*>(r0 + 4 * lane);
            unsigned int t0 = reinterpret_cast<const unsigned short*>(r0)[256 + lane];
            A0x += __uint_as_float((unsigned int)q0.x << 16);
            A0y += __uint_as_float((unsigned int)q0.y << 16);
            A0z += __uint_as_float((unsigned int)q0.z << 16);
            A0w += __uint_as_float((unsigned int)q0.w << 16);
            A0t += __uint_as_float(t0 << 16);
        }
        float sv = SVl[v];
        float rx = A0x + A1x + A2x + A3x + sv;
        float ry = A0y + A1y + A2y + A3y + sv;
        float rz = A0z + A1z + A2z + A3z + sv;
        float rw = A0w + A1w + A2w + A3w + sv;
        float rt = A0t + A1t + A2t + A3t + sv;
        sx += rx; qx = fmaf(rx, rx, qx);
        sy += ry; qy = fmaf(ry, ry, qy);
        sz += rz; qz = fmaf(rz, rz, qz);
        sw += rw; qw = fmaf(rw, rw, qw);
        st += rt; qt = fmaf(rt, rt, qt);
        __hip_bfloat16* out = AH + (size_t)v * DP;
        union { ushort4 u; __hip_bfloat16 h[4]; } o;
        o.h[0] = __float2bfloat16(rx); o.h[1] = __float2bfloat16(ry);
        o.h[2] = __float2bfloat16(rz); o.h[3] = __float2bfloat16(rw);
        *reinterpret_cast<ushort4*>(out + 4 * lane) = o.u;
        out[256 + lane] = __float2bfloat16(lane < 44 ? rt : 0.f);  // 300..319 -> 0
    }
    // reduce 4 waves -> per-block partials
    __shared__ float red[4 * 640];    // 10.24 KB
    float* rw_ = red + w * 640;
    rw_[4 * lane + 0] = sx; rw_[4 * lane + 1] = sy;
    rw_[4 * lane + 2] = sz; rw_[4 * lane + 3] = sw;
    rw_[256 + lane] = (lane < 44) ? st : 0.f;
    rw_[320 + 4 * lane + 0] = qx; rw_[320 + 4 * lane + 1] = qy;
    rw_[320 + 4 * lane + 2] = qz; rw_[320 + 4 * lane + 3] = qw;
    rw_[320 + 256 + lane] = (lane < 44) ? qt : 0.f;
    __syncthreads();
    for (int i = threadIdx.x; i < 640; i += 256)
        part[(size_t)blockIdx.x * 640 + i] =
            red[i] + red[640 + i] + red[1280 + i] + red[1920 + i];
}

// reduce AGGB partials -> 64 partials  (AGGB = 64*49)
__global__ void finalize1_kernel(const float* __restrict__ part, float* __restrict__ part2) {
    int b = blockIdx.x;                 // 0..63
    const int K = AGGB / 64;            // 49
    for (int i = threadIdx.x; i < 640; i += 256) {
        float acc = 0.f;
        for (int k = 0; k < K; ++k)
            acc += part[(size_t)(b * K + k) * 640 + i];
        part2[b * 640 + i] = acc;
    }
}

// reduce 64 partials; writes scale/shift for ALL 320 dims (pad dims 0/0)
__global__ void finalize_kernel(const float* __restrict__ part2,
                                const float* __restrict__ gamma_l,
                                const float* __restrict__ beta_l,
                                float* __restrict__ scale, float* __restrict__ shift) {
    int d = threadIdx.x;                 // block of 320
    float sc = 0.f, sh = 0.f;
    if (d < DD) {
        float s = 0.f, q = 0.f;
        for (int b = 0; b < 64; ++b) {
            s += part2[b * 640 + d];
            q += part2[b * 640 + 320 + d];
        }
        const float invN = 1.0f / (float)NN;
        float mean = s * invN;
        float var = q * invN - mean * mean;
        var = fmaxf(var, 0.f);                      // guard fp32 cancellation
        float rs = rsqrtf(var + 1e-5f);
        sc = rs * gamma_l[d];
        sh = beta_l[d] - mean * sc;
    }
    scale[d] = sc;
    shift[d] = sh;
}

// ---------------------------------------------------------------------------
__device__ __forceinline__ int lower_bound_dev(const int* b, int n, int key) {
    int lo = 0, hi = n;
    while (lo < hi) { int mid = (lo + hi) >> 1; if (b[mid] < key) lo = mid + 1; else hi = mid; }
    return lo;
}

// mean pool per graph over raw h_pre, then the last layer's BN affine applied
// after pooling (linear). One wave per graph; 16B loads on lanes 0..39.
__global__ void pool_kernel(const __hip_bfloat16* __restrict__ A, const int* __restrict__ batch,
                            const float* __restrict__ scale, const float* __restrict__ shift,
                            float* __restrict__ HG) {
    int g = blockIdx.x * 4 + (threadIdx.x >> 6);
    int lane = threadIdx.x & 63;
    bool act = lane < 40;
    int lo = lower_bound_dev(batch, NN, g);
    int hi = lower_bound_dev(batch, NN, g + 1);
    const int4 z4 = make_int4(0, 0, 0, 0);
    float a[8];
#pragma unroll
    for (int j = 0; j < 8; ++j) a[j] = 0.f;
    for (int v = lo; v < hi; ++v) {
        int4 q = act ? *reinterpret_cast<const int4*>(A + (size_t)v * DP + 8 * lane) : z4;
        addbf8(a, q);
    }
    if (act) {
        int cnt = hi - lo;
        float inv = 1.0f / (float)(cnt > 0 ? cnt : 1);
        float* out = HG + (size_t)g * DP;
#pragma unroll
        for (int j = 0; j < 8; ++j) {
            int d = 8 * lane + j;
            out[d] = fmaf(a[j] * inv, scale[d], shift[d]);  // pad dims: 0/0 -> 0
        }
    }
}

// h_feat = hg @ feat_w + feat_b   (one block per graph), f32 out
__global__ void feat_kernel(const float* __restrict__ HG,
                            const float* __restrict__ fw,
                            const float* __restrict__ fb,
                            float* __restrict__ HFEAT, float* __restrict__ out0) {
    __shared__ float hgs[DD];
    int g = blockIdx.x, tid = threadIdx.x;
    for (int i = tid; i < DD; i += 256) hgs[i] = HG[(size_t)g * DP + i];
    __syncthreads();
    float acc = fb[tid];
#pragma unroll 4
    for (int k = 0; k < DD; ++k)
        acc = fmaf(hgs[k], fw[k * FEAT + tid], acc);
    HFEAT[g * FEAT + tid] = acc;
    out0[g * FEAT + tid] = acc;
}

// out = relu(h_feat @ w1 + b1) @ w2 + b2   (one block per graph), f32 out
__global__ void mlp_kernel(const float* __restrict__ HFEAT,
                           const float* __restrict__ w1, const float* __restrict__ b1,
                           const float* __restrict__ w2, const float* __restrict__ b2,
                           float* __restrict__ out1) {
    __shared__ float hf[FEAT], t[FEAT];
    int g = blockIdx.x, tid = threadIdx.x;
    hf[tid] = HFEAT[g * FEAT + tid];
    __syncthreads();
    float acc = b1[tid];
#pragma unroll 4
    for (int k = 0; k < FEAT; ++k)
        acc = fmaf(hf[k], w1[k * FEAT + tid], acc);
    t[tid] = fmaxf(acc, 0.f);
    __syncthreads();
    if (tid < FEAT / 2) {
        float acc2 = b2[tid];
#pragma unroll 4
        for (int k = 0; k < FEAT; ++k)
            acc2 = fmaf(t[k], w2[k * (FEAT / 2) + tid], acc2);
        out1[g * (FEAT / 2) + tid] = acc2;
    }
}

// ---------------------------------------------------------------------------
extern "C" void kernel_launch(void* const* d_in, const int* in_sizes, int n_in,
                              void* d_out, int out_size, void* d_ws, size_t ws_size,
                              hipStream_t stream) {
    const int* x     = (const int*)d_in[0];
    const int* ei    = (const int*)d_in[1];
    const int* ea    = (const int*)d_in[2];
    const int* batch = (const int*)d_in[3];
    const float* emb1  = (const float*)d_in[4];
    const float* emb2  = (const float*)d_in[5];
    const float* W     = (const float*)d_in[6];
    // d_in[7] = b[l]: per-dim constant, cancelled by BatchNorm -> unused
    const float* e1    = (const float*)d_in[8];
    const float* e2    = (const float*)d_in[9];
    const float* gamma = (const float*)d_in[10];
    const float* beta  = (const float*)d_in[11];
    const float* fw    = (const float*)d_in[12];
    const float* fb    = (const float*)d_in[13];
    const float* w1    = (const float*)d_in[14];
    const float* b1    = (const float*)d_in[15];
    const float* w2    = (const float*)d_in[16];
    const float* b2    = (const float*)d_in[17];

    // workspace carve (~80 MB total; small control buffers FIRST)
    char* base = (char*)d_ws;
    size_t off = 0;
    auto carve = [&](size_t bytes) -> void* {
        void* p = base + off;
        off = (off + bytes + 255) & ~(size_t)255;
        return p;
    };
    int*            PTR   = (int*)carve((size_t)(NN + 1) * 4);
    int*            CUR   = (int*)carve((size_t)NN * 4);
    int*            SRC   = (int*)carve((size_t)EE * 4);
    float*          SV    = (float*)carve((size_t)LL * NN * 4);
    int*            BSUM  = (int*)carve(256 * 4);
    float*          PART  = (float*)carve((size_t)AGGB * 640 * 4);
    float*          PART2 = (float*)carve((size_t)64 * 640 * 4);
    float*          SCALE = (float*)carve(DP * 4);
    float*          SHIFT = (float*)carve(DP * 4);
    float*          HG    = (float*)carve((size_t)GG * DP * 4);
    float*          HFEAT = (float*)carve((size_t)GG * FEAT * 4);
    __hip_bfloat16* WT    = (__hip_bfloat16*)carve((size_t)LL * DP * DP * 2);
    __hip_bfloat16* AH    = (__hip_bfloat16*)carve((size_t)NN * DP * 2);  // h_pre ping
    __hip_bfloat16* HWb   = (__hip_bfloat16*)carve((size_t)NN * DP * 2);  // gemm out pong

    float* out0 = (float*)d_out;                 // h_feat [G,256] f32
    float* out1 = (float*)d_out + GG * FEAT;     // out    [G,128] f32

    // ---- preprocess (ws is re-poisoned before every call) ----
    hipMemsetAsync(CUR, 0, (size_t)NN * 4, stream);
    hist_kernel<<<EE / 256, 256, 0, stream>>>(ei, CUR);
    scan1_kernel<<<196, 256, 0, stream>>>(CUR, PTR, BSUM);
    scan2_kernel<<<1, 256, 0, stream>>>(BSUM);
    scan3_kernel<<<196, 256, 0, stream>>>(PTR, BSUM);
    hipMemsetAsync(CUR, 0, (size_t)NN * 4, stream);
    scatter_kernel<<<EE / 256, 256, 0, stream>>>(ei, ea, PTR, CUR, SRC);
    sv_kernel<<<196, 256, 0, stream>>>(PTR, SRC, e1, e2, SV);
    repack_kernel<<<(LL * DP * DP) / 256, 256, 0, stream>>>(W, WT);

    // ---- layers (l=0: embedding computed inside gemm A-staging; l>0: BN+relu
    //       of layer l-1 folded into gemm A-staging; BN stats fused into agg) ----
    for (int l = 0; l < LL; ++l) {
        gemm_kernel<<<dim3(391, 2), 256, 0, stream>>>(
            AH, WT + (size_t)l * DP * DP, HWb, NN, SCALE, SHIFT,
            x, emb1, emb2, l == 0 ? 2 : 1);
        agg_kernel<<<AGGB, 256, 0, stream>>>(HWb, PTR, SRC, SV + (size_t)l * NN, AH, PART);
        finalize1_kernel<<<64, 256, 0, stream>>>(PART, PART2);
        finalize_kernel<<<1, 320, 0, stream>>>(PART2, gamma + l * DD, beta + l * DD, SCALE, SHIFT);
    }

    // ---- head (BN affine of last layer applied after pooling — linear) ----
    pool_kernel<<<GG / 4, 256, 0, stream>>>(AH, batch, SCALE, SHIFT, HG);
    feat_kernel<<<GG, 256, 0, stream>>>(HG, fw, fb, HFEAT, out0);
    mlp_kernel<<<GG, 256, 0, stream>>>(HFEAT, w1, b1, w2, b2, out1);
}